// Round 5
// baseline (111.337 us; speedup 1.0000x reference)
//
#include <hip/hip_runtime.h>
#include <hip/hip_bf16.h>

typedef __attribute__((ext_vector_type(4)))  float f32x4;
typedef __attribute__((ext_vector_type(16))) float f32x16;
typedef __attribute__((ext_vector_type(8)))  short bf16x8;

#define LOG2E 1.44269504088896340736f

// native v_exp_f32 (1 instr, ~1 ulp); plain exp2f lowers to precise OCML (~30 cyc).
#if __has_builtin(__builtin_amdgcn_exp2f)
static __device__ __forceinline__ float exp2_native(float x) {
  return __builtin_amdgcn_exp2f(x);
}
#else
extern "C" __device__ float __ocml_native_exp2_f32(float);
static __device__ __forceinline__ float exp2_native(float x) {
  return __ocml_native_exp2_f32(x);
}
#endif

// bf16 truncation pack: low ushort <- a, high ushort <- b (1x v_perm_b32).
static __device__ __forceinline__ unsigned int pack_trunc_f(float a, float b) {
  return __builtin_amdgcn_perm(__float_as_uint(b), __float_as_uint(a), 0x07060302);
}

// async global->LDS, 16B/lane: LDS dest = wave-uniform base + lane*16 (HW adds)
typedef const __attribute__((address_space(1))) unsigned int gu32;
typedef __attribute__((address_space(3))) unsigned int lu32;
static __device__ __forceinline__ void gload_lds16(const void* g, void* l) {
  __builtin_amdgcn_global_load_lds((gu32*)g, (lu32*)l, 16, 0, 0);
}

// ---------------------------------------------------------------------------
// proj: y = x(32768x64) * K^T(64x80) via MFMA 16x16x32. Block=256thr/4 waves.
// g-columns pre-scaled by log2(e) so attn can use native exp2 directly.
// h stored per 128-key tile as [c][136] bf16 (8-slot pad, garbage) with keys
// at PERMUTED position kpos = bitswap2<->3(key&127): attn's S^T C-layout ==
// PV A-layout with contiguous B-frags. (Stride 136 = 68 words == 4 mod 32:
// 8-lane b128 phases hit distinct banks -> 0 conflicts, measured R4/R5.)
// ---------------------------------------------------------------------------
__global__ __launch_bounds__(256) void proj_kernel(
    const float* __restrict__ x, const float* __restrict__ kf,
    const float* __restrict__ kg, const float* __restrict__ kh,
    unsigned short* __restrict__ f_b, unsigned short* __restrict__ g_b,
    unsigned short* __restrict__ h_p)
{
  __shared__ unsigned short Kt[80*72];
  const int t = threadIdx.x, blk = blockIdx.x;

  #pragma unroll
  for (int r = 0; r < 20; ++r) {
    int idx = r*256 + t;                 // 5120 = 80x64
    int o = idx >> 6, c = idx & 63;
    float v = (o < 8) ? kf[c*8 + o]
            : (o < 16) ? kg[c*8 + (o-8)] * LOG2E
            : kh[c*64 + (o-16)];
    Kt[o*72 + c] = (unsigned short)(__float_as_uint(v) >> 16);
  }
  __syncthreads();

  const int w = t >> 6, lane = t & 63, l15 = lane & 15, quad = lane >> 4;
  const int Rbase = blk*64 + w*16;
  const int R = Rbase + l15;

  bf16x8 af[2];
  #pragma unroll
  for (int kk = 0; kk < 2; ++kk) {
    const float* xp = x + (long)R*64 + kk*32 + quad*8;
    float4 v0 = *(const float4*)xp;
    float4 v1 = *(const float4*)(xp + 4);
    union { unsigned int u[4]; bf16x8 v; } p;
    p.u[0] = pack_trunc_f(v0.x, v0.y);
    p.u[1] = pack_trunc_f(v0.z, v0.w);
    p.u[2] = pack_trunc_f(v1.x, v1.y);
    p.u[3] = pack_trunc_f(v1.z, v1.w);
    af[kk] = p.v;
  }

  f32x4 acc[5];
  #pragma unroll
  for (int nt = 0; nt < 5; ++nt) { f32x4 z = {}; acc[nt] = z; }

  #pragma unroll
  for (int nt = 0; nt < 5; ++nt)
    #pragma unroll
    for (int kk = 0; kk < 2; ++kk) {
      bf16x8 bfv = *(const bf16x8*)&Kt[(nt*16 + l15)*72 + kk*32 + quad*8];
      acc[nt] = __builtin_amdgcn_mfma_f32_16x16x32_bf16(af[kk], bfv, acc[nt], 0, 0, 0);
    }

  const int bt = Rbase >> 12;
  const int kt = (Rbase >> 7) & 31;
  const int base = ((blk & 1) << 6) + (w << 4);
  // permuted store position: swap bits 2<->3 of (base + 4*quad + rr)
  const int pi = base + ((quad & 1) << 3) + (((quad >> 1) & 1) << 2);

  #pragma unroll
  for (int rr = 0; rr < 4; ++rr) {
    const int nq = (Rbase + quad*4 + rr) & 4095;
    unsigned short v = (unsigned short)(__float_as_uint(acc[0][rr]) >> 16);
    if (l15 < 8) f_b[((long)bt*4096 + nq)*8 + l15] = v;
    else         g_b[((long)bt*4096 + nq)*8 + (l15 - 8)] = v;
  }
  #pragma unroll
  for (int nt = 1; nt < 5; ++nt) {
    const int c = (nt - 1)*16 + l15;
    uint2 v;
    v.x = pack_trunc_f(acc[nt][0], acc[nt][1]);
    v.y = pack_trunc_f(acc[nt][2], acc[nt][3]);
    *(uint2*)(h_p + ((long)(bt*32 + kt)*64 + c)*136 + pi) = v;
  }
}

// ---------------------------------------------------------------------------
// attn: full-K flash attention, intra-block 4-way key split WITHIN each tile.
// Grid (128 qtiles, 8 batch) = 1024 blocks; block = 256 thr = 4 waves, all
// waves share the SAME 32 queries; wave w computes subtile mt=w (keys
// w*32..w*32+31 in permuted storage order) of every 128-key tile.
// ONE double-buffered tile stream (2 x 19456 = 38912 B dynamic LDS) shared
// by all 4 waves -> 4 blocks/CU (155,648 B) -> 16 waves/CU = 4 waves/SIMD:
// twice R4's occupancy, which is what hides the sc->exp2->pack->PV chain.
// One barrier per tile: barrier (drains tile-t loads) -> issue tile-t+1
// loads (staging split 4-ways across waves) -> compute tile t.
// l accumulated via ones-column PV MFMA (col 0).
// Combine: waves 1-3 dump 48 f32/lane into LDS slots with stride 49 words
// (17*l mod 32 is a lane-bijection -> conflict-free; R4's stride-48 was a
// 32-way conflict, 2.95M conflict-cycles measured); wave 0 sums and writes
// out = gamma*o/l + x. No fences, no extra dispatch (R2 lesson).
// ---------------------------------------------------------------------------
__global__ __launch_bounds__(256, 4) void attn_kernel(
    const unsigned short* __restrict__ f_b, const unsigned short* __restrict__ g_b,
    const unsigned short* __restrict__ h_p,
    const float* __restrict__ x, const float* __restrict__ gamma_p,
    float* __restrict__ out)
{
  extern __shared__ char smem[];   // 38912 B: tile buf bi at bi*19456; combine reuses

  const int t = threadIdx.x;
  const int w = t >> 6, lane = t & 63, l31 = lane & 31, a = lane >> 5;
  const int qb = blockIdx.x, b = blockIdx.y;
  const int q0 = qb*32;

  // g B-frag: n = q = l31, k = a*8+j ; real only at a=0 (K=8 zero-padded)
  bf16x8 gfv;
  {
    bf16x8 gv = *(const bf16x8*)(g_b + ((long)b*4096 + q0 + l31)*8);
    bf16x8 z = {};
    gfv = (a == 0) ? gv : z;
  }
  // ones B-frag (col 0 only): accumulates l = sum_k P via the PV MFMA
  bf16x8 bhl;
  {
    union { unsigned short s[8]; bf16x8 v; } o8;
    #pragma unroll
    for (int j = 0; j < 8; ++j) o8.s[j] = 0x3F80;   // bf16 1.0
    bf16x8 z = {};
    bhl = (l31 == 0) ? o8.v : z;
  }

  f32x16 oacc[2], ol;
  { f32x16 z = {}; oacc[0] = z; oacc[1] = z; ol = z; }

  const char* hp_b = (const char*)h_p + (long)b*32*17408;
  const char* fb_b = (const char*)f_b + (long)b*4096*16;

  // stage tile kt into buffer bi: 19 chunks of 1024 B, wave w takes chunks
  // c = i*4 + w (counts 5,5,5,4). Chunks 0-16 = h tile, 17-18 = f tile.
  auto stage = [&](int bi, int kt) {
    const char* hsrc = hp_b + (long)kt*17408;
    const char* fsrc = fb_b + (long)kt*2048;
    char* dst = smem + bi*19456;
    #pragma unroll
    for (int i = 0; i < 5; ++i) {
      const int c = i*4 + w;
      if (c < 19) {
        const int off = c*1024;
        const char* src = (off < 17408) ? (hsrc + off) : (fsrc + (off - 17408));
        gload_lds16(src + lane*16, dst + off);
      }
    }
  };

  stage(0, 0);

  for (int ktl = 0; ktl < 32; ++ktl) {
    __syncthreads();                     // drains tile-ktl loads; protects reuse
    if (ktl < 31) stage((ktl + 1) & 1, ktl + 1);

    const unsigned short* hts = (const unsigned short*)(smem + (ktl & 1)*19456);
    const unsigned short* fts = hts + 8704;   // f block at byte 17408

    // this wave's subtile: mt = w (keys w*32.. in storage order)
    bf16x8 afv = *(const bf16x8*)&fts[(w*32 + l31)*8];
    f32x16 zz = {};
    f32x16 sc = __builtin_amdgcn_mfma_f32_32x32x16_bf16(afv, gfv, zz, 0, 0, 0);

    #pragma unroll
    for (int half = 0; half < 2; ++half) {
      const int s = w*2 + half;          // PV K-step: contraction k in [16s,16s+16)
      bf16x8 bh0 = *(const bf16x8*)&hts[(l31)*136      + s*16 + a*8];
      bf16x8 bh1 = *(const bf16x8*)&hts[(32 + l31)*136 + s*16 + a*8];
      union { unsigned int u[4]; bf16x8 v; } ap;
      #pragma unroll
      for (int j = 0; j < 4; ++j) {
        float ea = exp2_native(sc[half*8 + 2*j]);      // g pre-scaled by log2e
        float eb = exp2_native(sc[half*8 + 2*j + 1]);
        ap.u[j] = pack_trunc_f(ea, eb);
      }
      oacc[0] = __builtin_amdgcn_mfma_f32_32x32x16_bf16(ap.v, bh0, oacc[0], 0, 0, 0);
      oacc[1] = __builtin_amdgcn_mfma_f32_32x32x16_bf16(ap.v, bh1, oacc[1], 0, 0, 0);
      ol      = __builtin_amdgcn_mfma_f32_32x32x16_bf16(ap.v, bhl, ol,      0, 0, 0);
    }
  }

  // ---- intra-block 4-way combine (LDS, stride 49 = conflict-free) ----
  __syncthreads();                       // all compute done; stream reusable
  float* cb = (float*)smem;              // 3 slots x 64 lanes x 49 words = 37632 B
  if (w > 0) {
    float* d = cb + ((w - 1)*64 + lane)*49;
    #pragma unroll
    for (int r = 0; r < 16; ++r) {
      d[r] = oacc[0][r]; d[16 + r] = oacc[1][r]; d[32 + r] = ol[r];
    }
  }
  __syncthreads();
  if (w == 0) {
    #pragma unroll
    for (int sl = 0; sl < 3; ++sl) {
      const float* sp = cb + (sl*64 + lane)*49;
      #pragma unroll
      for (int r = 0; r < 16; ++r) {
        oacc[0][r] += sp[r]; oacc[1][r] += sp[16 + r]; ol[r] += sp[32 + r];
      }
    }

    const float gamma = gamma_p[0];
    const float* xb = x + ((long)b*4096 + q0)*64;
    float* ob = out + ((long)b*4096 + q0)*64;

    #pragma unroll
    for (int r = 0; r < 16; ++r) {
      const int q = (r & 3) + 8*(r >> 2) + 4*a;     // C row for this acc reg
      // l for row q lives in col-0 lane of this 32-half (lane 0 / lane 32)
      const float lq = __shfl(ol[r], lane & 32);
      const float s = gamma / lq;
      #pragma unroll
      for (int nt = 0; nt < 2; ++nt) {
        const long idx = (long)q*64 + nt*32 + l31;  // col c = nt*32+l31
        ob[idx] = fmaf(s, oacc[nt][r], xb[idx]);
      }
    }
  }
}

extern "C" void kernel_launch(void* const* d_in, const int* in_sizes, int n_in,
                              void* d_out, int out_size, void* d_ws, size_t ws_size,
                              hipStream_t stream) {
  const float* x  = (const float*)d_in[0];
  const float* kf = (const float*)d_in[1];
  const float* kg = (const float*)d_in[2];
  const float* kh = (const float*)d_in[3];
  const float* gamma = (const float*)d_in[4];
  float* out = (float*)d_out;

  char* ws = (char*)d_ws;
  unsigned short* h_p = (unsigned short*)ws;                  // 8*32*64*136*2 = 4,456,448
  unsigned short* f_b = (unsigned short*)(ws + 4456448);      // 524,288
  unsigned short* g_b = (unsigned short*)(ws + 4980736);      // 524,288

  proj_kernel<<<512, 256, 0, stream>>>(x, kf, kg, kh, f_b, g_b, h_p);
  attn_kernel<<<dim3(128, 8), 256, 38912, stream>>>(f_b, g_b, h_p, x, gamma, out);
}

// Round 6
// 104.619 us; speedup vs baseline: 1.0642x; 1.0642x over previous
//
#include <hip/hip_runtime.h>
#include <hip/hip_bf16.h>

typedef __attribute__((ext_vector_type(4)))  float f32x4;
typedef __attribute__((ext_vector_type(16))) float f32x16;
typedef __attribute__((ext_vector_type(8)))  short bf16x8;

#define LOG2E 1.44269504088896340736f

// native v_exp_f32 (1 instr, ~1 ulp); plain exp2f lowers to precise OCML (~30 cyc).
#if __has_builtin(__builtin_amdgcn_exp2f)
static __device__ __forceinline__ float exp2_native(float x) {
  return __builtin_amdgcn_exp2f(x);
}
#else
extern "C" __device__ float __ocml_native_exp2_f32(float);
static __device__ __forceinline__ float exp2_native(float x) {
  return __ocml_native_exp2_f32(x);
}
#endif

// bf16 truncation pack: low ushort <- a, high ushort <- b (1x v_perm_b32).
static __device__ __forceinline__ unsigned int pack_trunc_f(float a, float b) {
  return __builtin_amdgcn_perm(__float_as_uint(b), __float_as_uint(a), 0x07060302);
}

// async global->LDS, 16B/lane: LDS dest = wave-uniform base + lane*16 (HW adds)
typedef const __attribute__((address_space(1))) unsigned int gu32;
typedef __attribute__((address_space(3))) unsigned int lu32;
static __device__ __forceinline__ void gload_lds16(const void* g, void* l) {
  __builtin_amdgcn_global_load_lds((gu32*)g, (lu32*)l, 16, 0, 0);
}

// ---------------------------------------------------------------------------
// proj: y = x(32768x64) * K^T(64x80) via MFMA 16x16x32. Block=256thr/4 waves.
// g-columns pre-scaled by log2(e) so attn can use native exp2 directly.
// h stored per 128-key tile as [c][136] bf16 (8-slot pad, garbage) with keys
// at PERMUTED position kpos = bitswap2<->3(key&127): attn's S^T C-layout ==
// PV A-layout with contiguous B-frags. (Stride 136 = 68 words == 4 mod 32:
// 8-lane b128 phases hit distinct banks -> 0 conflicts, measured R4/R5.)
// XCD-batch pinning: block id -> blk = (id&7)*64 + id>>3, so batch
// bt = blk>>6 = id&7 == id%8 == XCD (round-robin dispatch): each batch's
// h_p/f_b/g_b writes land (and stay) in that XCD's L2 for attn to re-read.
// ---------------------------------------------------------------------------
__global__ __launch_bounds__(256) void proj_kernel(
    const float* __restrict__ x, const float* __restrict__ kf,
    const float* __restrict__ kg, const float* __restrict__ kh,
    unsigned short* __restrict__ f_b, unsigned short* __restrict__ g_b,
    unsigned short* __restrict__ h_p)
{
  __shared__ unsigned short Kt[80*72];
  const int t = threadIdx.x;
  const int idb = blockIdx.x;
  const int blk = (idb & 7)*64 + (idb >> 3);   // batch = blk>>6 = idb&7 = XCD

  #pragma unroll
  for (int r = 0; r < 20; ++r) {
    int idx = r*256 + t;                 // 5120 = 80x64
    int o = idx >> 6, c = idx & 63;
    float v = (o < 8) ? kf[c*8 + o]
            : (o < 16) ? kg[c*8 + (o-8)] * LOG2E
            : kh[c*64 + (o-16)];
    Kt[o*72 + c] = (unsigned short)(__float_as_uint(v) >> 16);
  }
  __syncthreads();

  const int w = t >> 6, lane = t & 63, l15 = lane & 15, quad = lane >> 4;
  const int Rbase = blk*64 + w*16;
  const int R = Rbase + l15;

  bf16x8 af[2];
  #pragma unroll
  for (int kk = 0; kk < 2; ++kk) {
    const float* xp = x + (long)R*64 + kk*32 + quad*8;
    float4 v0 = *(const float4*)xp;
    float4 v1 = *(const float4*)(xp + 4);
    union { unsigned int u[4]; bf16x8 v; } p;
    p.u[0] = pack_trunc_f(v0.x, v0.y);
    p.u[1] = pack_trunc_f(v0.z, v0.w);
    p.u[2] = pack_trunc_f(v1.x, v1.y);
    p.u[3] = pack_trunc_f(v1.z, v1.w);
    af[kk] = p.v;
  }

  f32x4 acc[5];
  #pragma unroll
  for (int nt = 0; nt < 5; ++nt) { f32x4 z = {}; acc[nt] = z; }

  #pragma unroll
  for (int nt = 0; nt < 5; ++nt)
    #pragma unroll
    for (int kk = 0; kk < 2; ++kk) {
      bf16x8 bfv = *(const bf16x8*)&Kt[(nt*16 + l15)*72 + kk*32 + quad*8];
      acc[nt] = __builtin_amdgcn_mfma_f32_16x16x32_bf16(af[kk], bfv, acc[nt], 0, 0, 0);
    }

  const int bt = Rbase >> 12;
  const int kt = (Rbase >> 7) & 31;
  const int base = ((blk & 1) << 6) + (w << 4);
  // permuted store position: swap bits 2<->3 of (base + 4*quad + rr)
  const int pi = base + ((quad & 1) << 3) + (((quad >> 1) & 1) << 2);

  #pragma unroll
  for (int rr = 0; rr < 4; ++rr) {
    const int nq = (Rbase + quad*4 + rr) & 4095;
    unsigned short v = (unsigned short)(__float_as_uint(acc[0][rr]) >> 16);
    if (l15 < 8) f_b[((long)bt*4096 + nq)*8 + l15] = v;
    else         g_b[((long)bt*4096 + nq)*8 + (l15 - 8)] = v;
  }
  #pragma unroll
  for (int nt = 1; nt < 5; ++nt) {
    const int c = (nt - 1)*16 + l15;
    uint2 v;
    v.x = pack_trunc_f(acc[nt][0], acc[nt][1]);
    v.y = pack_trunc_f(acc[nt][2], acc[nt][3]);
    *(uint2*)(h_p + ((long)(bt*32 + kt)*64 + c)*136 + pi) = v;
  }
}

// ---------------------------------------------------------------------------
// attn: full-K flash attention, 64 queries/block, 8 waves (512 thr):
// wave (qg, ks) = (w&1, w>>1): q-group qg owns 32 queries, wave computes
// key-subtile ks (keys ks*32.. in permuted storage order) of every 128-key
// tile. ONE double-buffered tile stream (2 x 19456 = 38912 B dynamic LDS)
// shared by all 8 waves -> 2 blocks/CU -> 16 waves/CU = 4 waves/SIMD (same
// as R5) while HALVING the L2->LDS staging volume (637 -> 318 MB: the
// R5 counter analysis showed staging volume, not occupancy, is the wall).
// XCD-batch pinning: 1-D grid, b = id&7 -> all blocks of batch b on XCD b
// (round-robin dispatch); per-XCD hot set 622 KB << 4 MiB L2 -> re-stages
// are local-L2 hits of data proj just wrote there.
// One barrier per tile: barrier (drains tile-t loads) -> issue tile-t+1
// loads (staging split 8-ways across waves) -> compute tile t.
// l accumulated via ones-column PV MFMA (col 0).
// Combine: sequential 3-round LDS reduction per q-group (stride 49 words =
// conflict-free, measured R5: 0 conflicts), ks=0 waves normalize and write
// out = gamma*o/l + x. No fences, no extra dispatch (R2 lesson).
// ---------------------------------------------------------------------------
__global__ __launch_bounds__(512, 4) void attn_kernel(
    const unsigned short* __restrict__ f_b, const unsigned short* __restrict__ g_b,
    const unsigned short* __restrict__ h_p,
    const float* __restrict__ x, const float* __restrict__ gamma_p,
    float* __restrict__ out)
{
  extern __shared__ char smem[];   // 38912 B: tile buf bi at bi*19456; combine reuses

  const int t = threadIdx.x;
  const int w = t >> 6, lane = t & 63, l31 = lane & 31, a = lane >> 5;
  const int qg = w & 1, ks = w >> 1;
  const int id = blockIdx.x;
  const int b = id & 7, qb = id >> 3;    // batch = XCD (round-robin)
  const int q0 = qb*64 + qg*32;

  // g B-frag: n = q = l31, k = a*8+j ; real only at a=0 (K=8 zero-padded)
  bf16x8 gfv;
  {
    bf16x8 gv = *(const bf16x8*)(g_b + ((long)b*4096 + q0 + l31)*8);
    bf16x8 z = {};
    gfv = (a == 0) ? gv : z;
  }
  // ones B-frag (col 0 only): accumulates l = sum_k P via the PV MFMA
  bf16x8 bhl;
  {
    union { unsigned short s[8]; bf16x8 v; } o8;
    #pragma unroll
    for (int j = 0; j < 8; ++j) o8.s[j] = 0x3F80;   // bf16 1.0
    bf16x8 z = {};
    bhl = (l31 == 0) ? o8.v : z;
  }

  f32x16 oacc[2], ol;
  { f32x16 z = {}; oacc[0] = z; oacc[1] = z; ol = z; }

  const char* hp_b = (const char*)h_p + (long)b*32*17408;
  const char* fb_b = (const char*)f_b + (long)b*4096*16;

  // stage tile kt into buffer bi: 19 chunks of 1024 B, wave w takes chunks
  // c = i*8 + w (counts 3,3,3,2,2,2,2,2). Chunks 0-16 = h tile, 17-18 = f.
  auto stage = [&](int bi, int kt) {
    const char* hsrc = hp_b + (long)kt*17408;
    const char* fsrc = fb_b + (long)kt*2048;
    char* dst = smem + bi*19456;
    #pragma unroll
    for (int i = 0; i < 3; ++i) {
      const int c = i*8 + w;
      if (c < 19) {
        const int off = c*1024;
        const char* src = (off < 17408) ? (hsrc + off) : (fsrc + (off - 17408));
        gload_lds16(src + lane*16, dst + off);
      }
    }
  };

  stage(0, 0);

  for (int ktl = 0; ktl < 32; ++ktl) {
    __syncthreads();                     // drains tile-ktl loads; protects reuse
    if (ktl < 31) stage((ktl + 1) & 1, ktl + 1);

    const unsigned short* hts = (const unsigned short*)(smem + (ktl & 1)*19456);
    const unsigned short* fts = hts + 8704;   // f block at byte 17408

    // this wave's subtile: mt = ks (keys ks*32.. in storage order)
    bf16x8 afv = *(const bf16x8*)&fts[(ks*32 + l31)*8];
    f32x16 zz = {};
    f32x16 sc = __builtin_amdgcn_mfma_f32_32x32x16_bf16(afv, gfv, zz, 0, 0, 0);

    #pragma unroll
    for (int half = 0; half < 2; ++half) {
      const int s = ks*2 + half;         // PV K-step: contraction k in [16s,16s+16)
      bf16x8 bh0 = *(const bf16x8*)&hts[(l31)*136      + s*16 + a*8];
      bf16x8 bh1 = *(const bf16x8*)&hts[(32 + l31)*136 + s*16 + a*8];
      union { unsigned int u[4]; bf16x8 v; } ap;
      #pragma unroll
      for (int j = 0; j < 4; ++j) {
        float ea = exp2_native(sc[half*8 + 2*j]);      // g pre-scaled by log2e
        float eb = exp2_native(sc[half*8 + 2*j + 1]);
        ap.u[j] = pack_trunc_f(ea, eb);
      }
      oacc[0] = __builtin_amdgcn_mfma_f32_32x32x16_bf16(ap.v, bh0, oacc[0], 0, 0, 0);
      oacc[1] = __builtin_amdgcn_mfma_f32_32x32x16_bf16(ap.v, bh1, oacc[1], 0, 0, 0);
      ol      = __builtin_amdgcn_mfma_f32_32x32x16_bf16(ap.v, bhl, ol,      0, 0, 0);
    }
  }

  // ---- intra-block 4-way combine per q-group (LDS, stride 49 words) ----
  // Sequential rounds keep the region at 2 slots x 12544 B = 25088 <= 38912.
  __syncthreads();                       // all compute done; stream reusable
  float* cb = (float*)smem;
  #pragma unroll
  for (int sl = 1; sl <= 3; ++sl) {
    if (ks == sl) {
      float* d = cb + (qg*64 + lane)*49;
      #pragma unroll
      for (int r = 0; r < 16; ++r) {
        d[r] = oacc[0][r]; d[16 + r] = oacc[1][r]; d[32 + r] = ol[r];
      }
    }
    __syncthreads();
    if (ks == 0) {
      const float* sp = cb + (qg*64 + lane)*49;
      #pragma unroll
      for (int r = 0; r < 16; ++r) {
        oacc[0][r] += sp[r]; oacc[1][r] += sp[16 + r]; ol[r] += sp[32 + r];
      }
    }
    __syncthreads();
  }

  if (ks == 0) {
    const float gamma = gamma_p[0];
    const float* xb = x + ((long)b*4096 + q0)*64;
    float* ob = out + ((long)b*4096 + q0)*64;

    #pragma unroll
    for (int r = 0; r < 16; ++r) {
      const int q = (r & 3) + 8*(r >> 2) + 4*a;     // C row for this acc reg
      // l for row q lives in col-0 lane of this 32-half (lane 0 / lane 32)
      const float lq = __shfl(ol[r], lane & 32);
      const float s = gamma / lq;
      #pragma unroll
      for (int nt = 0; nt < 2; ++nt) {
        const long idx = (long)q*64 + nt*32 + l31;  // col c = nt*32+l31
        ob[idx] = fmaf(s, oacc[nt][r], xb[idx]);
      }
    }
  }
}

extern "C" void kernel_launch(void* const* d_in, const int* in_sizes, int n_in,
                              void* d_out, int out_size, void* d_ws, size_t ws_size,
                              hipStream_t stream) {
  const float* x  = (const float*)d_in[0];
  const float* kf = (const float*)d_in[1];
  const float* kg = (const float*)d_in[2];
  const float* kh = (const float*)d_in[3];
  const float* gamma = (const float*)d_in[4];
  float* out = (float*)d_out;

  char* ws = (char*)d_ws;
  unsigned short* h_p = (unsigned short*)ws;                  // 8*32*64*136*2 = 4,456,448
  unsigned short* f_b = (unsigned short*)(ws + 4456448);      // 524,288
  unsigned short* g_b = (unsigned short*)(ws + 4980736);      // 524,288

  proj_kernel<<<512, 256, 0, stream>>>(x, kf, kg, kh, f_b, g_b, h_p);
  attn_kernel<<<512, 512, 38912, stream>>>(f_b, g_b, h_p, x, gamma, out);
}

// Round 7
// 102.932 us; speedup vs baseline: 1.0817x; 1.0164x over previous
//
#include <hip/hip_runtime.h>
#include <hip/hip_bf16.h>

typedef __attribute__((ext_vector_type(4)))  float f32x4;
typedef __attribute__((ext_vector_type(16))) float f32x16;
typedef __attribute__((ext_vector_type(8)))  short bf16x8;

#define LOG2E 1.44269504088896340736f

// native v_exp_f32 (1 instr, ~1 ulp); plain exp2f lowers to precise OCML (~30 cyc).
#if __has_builtin(__builtin_amdgcn_exp2f)
static __device__ __forceinline__ float exp2_native(float x) {
  return __builtin_amdgcn_exp2f(x);
}
#else
extern "C" __device__ float __ocml_native_exp2_f32(float);
static __device__ __forceinline__ float exp2_native(float x) {
  return __ocml_native_exp2_f32(x);
}
#endif

// bf16 truncation pack: low ushort <- a, high ushort <- b (1x v_perm_b32).
static __device__ __forceinline__ unsigned int pack_trunc_f(float a, float b) {
  return __builtin_amdgcn_perm(__float_as_uint(b), __float_as_uint(a), 0x07060302);
}

// async global->LDS, 16B/lane: LDS dest = wave-uniform base + lane*16 (HW adds)
typedef const __attribute__((address_space(1))) unsigned int gu32;
typedef __attribute__((address_space(3))) unsigned int lu32;
static __device__ __forceinline__ void gload_lds16(const void* g, void* l) {
  __builtin_amdgcn_global_load_lds((gu32*)g, (lu32*)l, 16, 0, 0);
}

// ---------------------------------------------------------------------------
// proj: y = x(32768x64) * K^T(64x80) via MFMA 16x16x32. Block=256thr/4 waves.
// g-columns pre-scaled by log2(e) so attn can use native exp2 directly.
// h stored per 128-key tile as [c][136] bf16 (8-slot pad, garbage) with keys
// at PERMUTED position kpos = bitswap2<->3(key&127): attn's S^T C-layout ==
// PV A-layout with contiguous B-frags. (Stride 136 = 68 words == 4 mod 32:
// 8-lane b128 phases hit distinct banks -> 0 conflicts, measured R4/R5.)
// XCD-batch pinning: block id -> blk = (id&7)*64 + id>>3, so batch
// bt = blk>>6 = id&7 == XCD (round-robin dispatch): each batch's
// h_p/f_b/g_b writes land (and stay) in that XCD's L2 for attn to re-read.
// ---------------------------------------------------------------------------
__global__ __launch_bounds__(256) void proj_kernel(
    const float* __restrict__ x, const float* __restrict__ kf,
    const float* __restrict__ kg, const float* __restrict__ kh,
    unsigned short* __restrict__ f_b, unsigned short* __restrict__ g_b,
    unsigned short* __restrict__ h_p)
{
  __shared__ unsigned short Kt[80*72];
  const int t = threadIdx.x;
  const int idb = blockIdx.x;
  const int blk = (idb & 7)*64 + (idb >> 3);   // batch = blk>>6 = idb&7 = XCD

  #pragma unroll
  for (int r = 0; r < 20; ++r) {
    int idx = r*256 + t;                 // 5120 = 80x64
    int o = idx >> 6, c = idx & 63;
    float v = (o < 8) ? kf[c*8 + o]
            : (o < 16) ? kg[c*8 + (o-8)] * LOG2E
            : kh[c*64 + (o-16)];
    Kt[o*72 + c] = (unsigned short)(__float_as_uint(v) >> 16);
  }
  __syncthreads();

  const int w = t >> 6, lane = t & 63, l15 = lane & 15, quad = lane >> 4;
  const int Rbase = blk*64 + w*16;
  const int R = Rbase + l15;

  bf16x8 af[2];
  #pragma unroll
  for (int kk = 0; kk < 2; ++kk) {
    const float* xp = x + (long)R*64 + kk*32 + quad*8;
    float4 v0 = *(const float4*)xp;
    float4 v1 = *(const float4*)(xp + 4);
    union { unsigned int u[4]; bf16x8 v; } p;
    p.u[0] = pack_trunc_f(v0.x, v0.y);
    p.u[1] = pack_trunc_f(v0.z, v0.w);
    p.u[2] = pack_trunc_f(v1.x, v1.y);
    p.u[3] = pack_trunc_f(v1.z, v1.w);
    af[kk] = p.v;
  }

  f32x4 acc[5];
  #pragma unroll
  for (int nt = 0; nt < 5; ++nt) { f32x4 z = {}; acc[nt] = z; }

  #pragma unroll
  for (int nt = 0; nt < 5; ++nt)
    #pragma unroll
    for (int kk = 0; kk < 2; ++kk) {
      bf16x8 bfv = *(const bf16x8*)&Kt[(nt*16 + l15)*72 + kk*32 + quad*8];
      acc[nt] = __builtin_amdgcn_mfma_f32_16x16x32_bf16(af[kk], bfv, acc[nt], 0, 0, 0);
    }

  const int bt = Rbase >> 12;
  const int kt = (Rbase >> 7) & 31;
  const int base = ((blk & 1) << 6) + (w << 4);
  // permuted store position: swap bits 2<->3 of (base + 4*quad + rr)
  const int pi = base + ((quad & 1) << 3) + (((quad >> 1) & 1) << 2);

  #pragma unroll
  for (int rr = 0; rr < 4; ++rr) {
    const int nq = (Rbase + quad*4 + rr) & 4095;
    unsigned short v = (unsigned short)(__float_as_uint(acc[0][rr]) >> 16);
    if (l15 < 8) f_b[((long)bt*4096 + nq)*8 + l15] = v;
    else         g_b[((long)bt*4096 + nq)*8 + (l15 - 8)] = v;
  }
  #pragma unroll
  for (int nt = 1; nt < 5; ++nt) {
    const int c = (nt - 1)*16 + l15;
    uint2 v;
    v.x = pack_trunc_f(acc[nt][0], acc[nt][1]);
    v.y = pack_trunc_f(acc[nt][2], acc[nt][3]);
    *(uint2*)(h_p + ((long)(bt*32 + kt)*64 + c)*136 + pi) = v;
  }
}

// ---------------------------------------------------------------------------
// attn: full-K flash attention, 128 queries/block, 1024 thr = 16 waves:
// wave (qg, ks) = (w&3, w>>2): q-group qg owns 32 queries, wave computes
// key-subtile ks (keys ks*32.. in permuted storage order) of every 128-key
// tile. DOUBLE tiles: each iteration stages TWO 128-key tiles (38912 B) in
// one double-buffered stream (2 x 38912 = 77824 B dynamic LDS), so each
// wave runs 2 independent sc->exp2->pack->PV chains per barrier (ILP) and
// the barrier count halves (16 total).
// Grid 256 blocks = 1 block/CU -> 16 waves/CU = 4 waves/SIMD (the measured
// plateau) while HALVING staging volume again (318 -> 159 MB; R4->R6 ladder
// showed staging volume, not occupancy, is the binding term).
// XCD-batch pinning: b = id&7 -> all 32 blocks of batch b on XCD b
// (round-robin dispatch); per-XCD hot set 622 KB << 4 MiB L2.
// l accumulated via ones-column PV MFMA (col 0).
// Combine: 4-way ks-reduction per q-group via LDS, stride 49 words
// (conflict-free, measured R5/R6: 0 conflicts), 2 rounds of 6 slots
// (75264 B <= 77824); ks=0 waves normalize and write out = gamma*o/l + x.
// No fences, no extra dispatch (R2 lesson).
// ---------------------------------------------------------------------------
__global__ __launch_bounds__(1024, 4) void attn_kernel(
    const unsigned short* __restrict__ f_b, const unsigned short* __restrict__ g_b,
    const unsigned short* __restrict__ h_p,
    const float* __restrict__ x, const float* __restrict__ gamma_p,
    float* __restrict__ out)
{
  extern __shared__ char smem[];   // 77824 B: dbl-tile buf bi at bi*38912

  const int t = threadIdx.x;
  const int w = t >> 6, lane = t & 63, l31 = lane & 31, a = lane >> 5;
  const int qg = w & 3, ks = w >> 2;
  const int id = blockIdx.x;
  const int b = id & 7, qb = id >> 3;    // batch = XCD (round-robin)
  const int q0 = qb*128 + qg*32;

  // g B-frag: n = q = l31, k = a*8+j ; real only at a=0 (K=8 zero-padded)
  bf16x8 gfv;
  {
    bf16x8 gv = *(const bf16x8*)(g_b + ((long)b*4096 + q0 + l31)*8);
    bf16x8 z = {};
    gfv = (a == 0) ? gv : z;
  }
  // ones B-frag (col 0 only): accumulates l = sum_k P via the PV MFMA
  bf16x8 bhl;
  {
    union { unsigned short s[8]; bf16x8 v; } o8;
    #pragma unroll
    for (int j = 0; j < 8; ++j) o8.s[j] = 0x3F80;   // bf16 1.0
    bf16x8 z = {};
    bhl = (l31 == 0) ? o8.v : z;
  }

  f32x16 oacc[2], ol;
  { f32x16 z = {}; oacc[0] = z; oacc[1] = z; ol = z; }

  const char* hp_b = (const char*)h_p + (long)b*32*17408;
  const char* fb_b = (const char*)f_b + (long)b*4096*16;

  // stage tile-PAIR {2*tp, 2*tp+1} into buffer bi: 38 chunks of 1024 B,
  // wave w takes chunks c = i*16 + w (counts 3,3,3,3,3,3,2,...,2).
  // Sub-tile layout: two consecutive 19456-B blocks (17408 h + 2048 f).
  auto stage = [&](int bi, int tp) {
    char* dst = smem + bi*38912;
    #pragma unroll
    for (int i = 0; i < 3; ++i) {
      const int c = i*16 + w;
      if (c < 38) {
        const int off = c*1024;
        const int sub = (off >= 19456);
        const int kt = tp*2 + sub;
        const int within = off - sub*19456;
        const char* src = (within < 17408)
            ? (hp_b + (long)kt*17408 + within)
            : (fb_b + (long)kt*2048 + (within - 17408));
        gload_lds16(src + lane*16, dst + off);
      }
    }
  };

  stage(0, 0);

  for (int tp = 0; tp < 16; ++tp) {
    __syncthreads();                     // drains pair-tp loads; protects reuse
    if (tp < 15) stage((tp + 1) & 1, tp + 1);

    const char* bufb = smem + (tp & 1)*38912;

    #pragma unroll
    for (int sub = 0; sub < 2; ++sub) {
      const unsigned short* hts = (const unsigned short*)(bufb + sub*19456);
      const unsigned short* fts = hts + 8704;   // f block at byte 17408

      // this wave's subtile: mt = ks (keys ks*32.. in storage order)
      bf16x8 afv = *(const bf16x8*)&fts[(ks*32 + l31)*8];
      f32x16 zz = {};
      f32x16 sc = __builtin_amdgcn_mfma_f32_32x32x16_bf16(afv, gfv, zz, 0, 0, 0);

      #pragma unroll
      for (int half = 0; half < 2; ++half) {
        const int s = ks*2 + half;       // PV K-step: contraction k in [16s,16s+16)
        bf16x8 bh0 = *(const bf16x8*)&hts[(l31)*136      + s*16 + a*8];
        bf16x8 bh1 = *(const bf16x8*)&hts[(32 + l31)*136 + s*16 + a*8];
        union { unsigned int u[4]; bf16x8 v; } ap;
        #pragma unroll
        for (int j = 0; j < 4; ++j) {
          float ea = exp2_native(sc[half*8 + 2*j]);      // g pre-scaled by log2e
          float eb = exp2_native(sc[half*8 + 2*j + 1]);
          ap.u[j] = pack_trunc_f(ea, eb);
        }
        oacc[0] = __builtin_amdgcn_mfma_f32_32x32x16_bf16(ap.v, bh0, oacc[0], 0, 0, 0);
        oacc[1] = __builtin_amdgcn_mfma_f32_32x32x16_bf16(ap.v, bh1, oacc[1], 0, 0, 0);
        ol      = __builtin_amdgcn_mfma_f32_32x32x16_bf16(ap.v, bhl, ol,      0, 0, 0);
      }
    }
  }

  // ---- 4-way ks-combine per q-group (LDS, stride 49 words, 2 rounds) ----
  __syncthreads();                       // all compute done; stream reusable
  float* cb = (float*)smem;
  #pragma unroll
  for (int rnd = 0; rnd < 2; ++rnd) {
    if ((qg >> 1) == rnd && ks > 0) {
      float* d = cb + (((qg & 1)*3 + (ks - 1))*64 + lane)*49;
      #pragma unroll
      for (int r = 0; r < 16; ++r) {
        d[r] = oacc[0][r]; d[16 + r] = oacc[1][r]; d[32 + r] = ol[r];
      }
    }
    __syncthreads();
    if ((qg >> 1) == rnd && ks == 0) {
      #pragma unroll
      for (int sl = 0; sl < 3; ++sl) {
        const float* sp = cb + (((qg & 1)*3 + sl)*64 + lane)*49;
        #pragma unroll
        for (int r = 0; r < 16; ++r) {
          oacc[0][r] += sp[r]; oacc[1][r] += sp[16 + r]; ol[r] += sp[32 + r];
        }
      }
    }
    __syncthreads();
  }

  if (ks == 0) {
    const float gamma = gamma_p[0];
    const float* xb = x + ((long)b*4096 + q0)*64;
    float* ob = out + ((long)b*4096 + q0)*64;

    #pragma unroll
    for (int r = 0; r < 16; ++r) {
      const int q = (r & 3) + 8*(r >> 2) + 4*a;     // C row for this acc reg
      // l for row q lives in col-0 lane of this 32-half (lane 0 / lane 32)
      const float lq = __shfl(ol[r], lane & 32);
      const float s = gamma / lq;
      #pragma unroll
      for (int nt = 0; nt < 2; ++nt) {
        const long idx = (long)q*64 + nt*32 + l31;  // col c = nt*32+l31
        ob[idx] = fmaf(s, oacc[nt][r], xb[idx]);
      }
    }
  }
}

extern "C" void kernel_launch(void* const* d_in, const int* in_sizes, int n_in,
                              void* d_out, int out_size, void* d_ws, size_t ws_size,
                              hipStream_t stream) {
  const float* x  = (const float*)d_in[0];
  const float* kf = (const float*)d_in[1];
  const float* kg = (const float*)d_in[2];
  const float* kh = (const float*)d_in[3];
  const float* gamma = (const float*)d_in[4];
  float* out = (float*)d_out;

  char* ws = (char*)d_ws;
  unsigned short* h_p = (unsigned short*)ws;                  // 8*32*64*136*2 = 4,456,448
  unsigned short* f_b = (unsigned short*)(ws + 4456448);      // 524,288
  unsigned short* g_b = (unsigned short*)(ws + 4980736);      // 524,288

  proj_kernel<<<512, 256, 0, stream>>>(x, kf, kg, kh, f_b, g_b, h_p);
  attn_kernel<<<256, 1024, 77824, stream>>>(f_b, g_b, h_p, x, gamma, out);
}